// Round 12
// baseline (376.051 us; speedup 1.0000x reference)
//
#include <hip/hip_runtime.h>

#define N_NODESC 100000
#define N_EDGESC 600000
#define E_TOTC   700000
#define NUM_GRAPHSC 512
#define NEG_SLOPE 0.2f
#define NEG_INF_ENC 0x007FFFFFu
#define SCAN_NB 128

typedef unsigned short ushort_t;
typedef __attribute__((ext_vector_type(8))) short bf16x8;   // 8 bf16 = 4 VGPR
typedef __attribute__((ext_vector_type(4))) float f32x4;    // MFMA accumulator

// monotone float<->uint mapping so unsigned atomicMax == float max
__device__ __forceinline__ unsigned enc_f32(float f) {
    unsigned u = __float_as_uint(f);
    return (u & 0x80000000u) ? ~u : (u | 0x80000000u);
}
__device__ __forceinline__ float dec_f32(unsigned u) {
    u = (u & 0x80000000u) ? (u ^ 0x80000000u) : ~u;
    return __uint_as_float(u);
}
// exact fp32->bf16 RNE (finite values) and bf16->fp32
__device__ __forceinline__ ushort_t f32_to_bf16(float f) {
    unsigned u = __float_as_uint(f);
    return (ushort_t)((u + 0x7FFFu + ((u >> 16) & 1u)) >> 16);
}
__device__ __forceinline__ float bf16_to_f32(ushort_t h) {
    return __uint_as_float(((unsigned)h) << 16);
}
__device__ __forceinline__ unsigned pack_bf16x2(float a, float b) {
    return (unsigned)f32_to_bf16(a) | ((unsigned)f32_to_bf16(b) << 16);
}

// fused init: msum=0, mmax=-inf, cnt=0, deg=0, and W1/W2 -> bf16 in MFMA
// B-fragment layout wPre[n][k] (contiguous 16B per frag -> LDS-free gemms)
__global__ __launch_bounds__(256) void init_all(float* __restrict__ msum,
                                                unsigned* __restrict__ mmax,
                                                float* __restrict__ cnt,
                                                int* __restrict__ deg,
                                                const float* __restrict__ W1,
                                                const float* __restrict__ W2,
                                                ushort_t* __restrict__ wPre1,
                                                ushort_t* __restrict__ wPre2) {
    int i = blockIdx.x * 256 + threadIdx.x;
    if (i < NUM_GRAPHSC * 64) { msum[i] = 0.f; mmax[i] = NEG_INF_ENC; }
    if (i < NUM_GRAPHSC) cnt[i] = 0.f;
    if (i < N_NODESC) deg[i] = 0;
    if (i < 128 * 128) {
        int n = i >> 7, k = i & 127;
        wPre1[n * 128 + k] = f32_to_bf16(W1[k * 128 + n]);
    } else if (i < 128 * 128 + 64 * 128) {
        int j = i - 128 * 128;
        int n = j >> 7, k = j & 127;
        wPre2[n * 128 + k] = f32_to_bf16(W2[k * 64 + n]);
    }
}

// ---------------- CSR build ----------------
__global__ __launch_bounds__(256) void hist_dst(const int* __restrict__ ei,
                                                int* __restrict__ deg) {
    int e = blockIdx.x * blockDim.x + threadIdx.x;
    if (e >= E_TOTC) return;
    int d = (e < N_EDGESC) ? ei[N_EDGESC + e] : e - N_EDGESC;
    atomicAdd(&deg[d], 1);
}

__global__ __launch_bounds__(256) void scan_partial(const int* __restrict__ deg,
                                                    int* __restrict__ bsum, int n) {
    __shared__ int red[256];
    int chunk = (n + SCAN_NB - 1) / SCAN_NB;
    int lo = blockIdx.x * chunk, hi = min(lo + chunk, n);
    int s = 0;
    for (int i = lo + threadIdx.x; i < hi; i += 256) s += deg[i];
    red[threadIdx.x] = s;
    __syncthreads();
    for (int d = 128; d; d >>= 1) {
        if (threadIdx.x < d) red[threadIdx.x] += red[threadIdx.x + d];
        __syncthreads();
    }
    if (threadIdx.x == 0) bsum[blockIdx.x] = red[0];
}

// block-local scan + carry; every block redundantly scans the 128 partials in
// LDS (cheap) -- merges the old scan_bsum dispatch away.
__global__ __launch_bounds__(256) void scan_final(const int* __restrict__ deg,
                                                  const int* __restrict__ bsum,
                                                  int* __restrict__ off, int n) {
    __shared__ int bs[SCAN_NB];
    __shared__ int tile[256];
    __shared__ int carry;
    int t = threadIdx.x;
    if (t < SCAN_NB) bs[t] = bsum[t];
    __syncthreads();
    for (int d = 1; d < SCAN_NB; d <<= 1) {
        int v = (t >= d && t < SCAN_NB) ? bs[t - d] : 0;
        __syncthreads();
        if (t < SCAN_NB) bs[t] += v;
        __syncthreads();
    }
    if (t == 0) carry = blockIdx.x ? bs[blockIdx.x - 1] : 0;
    __syncthreads();
    int chunk = (n + SCAN_NB - 1) / SCAN_NB;
    int lo = blockIdx.x * chunk, hi = min(lo + chunk, n);
    for (int base = lo; base < hi; base += 256) {
        int i = base + t;
        int v = (i < hi) ? deg[i] : 0;
        tile[t] = v;
        __syncthreads();
        for (int d = 1; d < 256; d <<= 1) {
            int u = (t >= d) ? tile[t - d] : 0;
            __syncthreads();
            tile[t] += u;
            __syncthreads();
        }
        if (i < hi) off[i] = carry + tile[t] - v;
        __syncthreads();
        if (t == 0) carry += tile[255];
        __syncthreads();
    }
}

__global__ __launch_bounds__(256) void scatter_csr(const int* __restrict__ ei,
                                                   int* __restrict__ off,
                                                   int* __restrict__ csr) {
    int e = blockIdx.x * blockDim.x + threadIdx.x;
    if (e >= E_TOTC) return;
    int s, d;
    if (e < N_EDGESC) { s = ei[e]; d = ei[N_EDGESC + e]; } else { s = d = e - N_EDGESC; }
    int slot = atomicAdd(&off[d], 1);
    csr[slot] = s;
}

// ---------------- MFMA GEMM, layer 1 (v3: LDS-free) ----------------
// B-frags read directly from pre-converted bf16 wPre1[n][k] (64 KB, L1/L2-hot;
// one contiguous 16B load per frag) -> no staging, no barrier, no LDS
// occupancy cap. A: fp32 -> bf16 packed inline; 8 loads hoisted per kc.
// Fragment maps (m89/m91): A[m=lane&15][k=quad*8+j], B[n=lane&15][k=quad*8+j],
// D[row=quad*4+r][col=lane&15]. Wave w: cols {16w..16w+15} U {64+16w..};
// output head-interleaved u32 (head0 lo, head1 hi).
__global__ __launch_bounds__(256) void gemm1_mfma(const float* __restrict__ X,
                                                  const ushort_t* __restrict__ Wp,
                                                  ushort_t* __restrict__ Y16, int N) {
    int tid = threadIdx.x;
    int wave = tid >> 6, lane = tid & 63;
    int quad = lane >> 4, l16 = lane & 15;
    size_t node0 = (size_t)blockIdx.x * 64;

    f32x4 acc[4][2];
#pragma unroll
    for (int rt = 0; rt < 4; ++rt)
#pragma unroll
        for (int ct = 0; ct < 2; ++ct) acc[rt][ct] = (f32x4){0.f, 0.f, 0.f, 0.f};

    const ushort_t* w0p = Wp + (size_t)(16 * wave + l16) * 128;
    const ushort_t* w1p = Wp + (size_t)(64 + 16 * wave + l16) * 128;

#pragma unroll
    for (int kc = 0; kc < 4; ++kc) {
        int kb = kc * 32 + quad * 8;
        // hoist: all 8 global loads in flight before any pack/MFMA
        float4 xa[4], xb[4];
#pragma unroll
        for (int rt = 0; rt < 4; ++rt) {
            size_t row = node0 + rt * 16 + l16;
            if (row >= (size_t)N) row = N - 1;  // clamp: rows >= N never stored
            const float* xp = X + row * 128 + kb;
            xa[rt] = *(const float4*)xp;
            xb[rt] = *(const float4*)(xp + 4);
        }
        bf16x8 b0 = *(const bf16x8*)(w0p + kb);
        bf16x8 b1 = *(const bf16x8*)(w1p + kb);
#pragma unroll
        for (int rt = 0; rt < 4; ++rt) {
            union { bf16x8 v; unsigned u[4]; } af;
            af.u[0] = pack_bf16x2(xa[rt].x, xa[rt].y);
            af.u[1] = pack_bf16x2(xa[rt].z, xa[rt].w);
            af.u[2] = pack_bf16x2(xb[rt].x, xb[rt].y);
            af.u[3] = pack_bf16x2(xb[rt].z, xb[rt].w);
            acc[rt][0] = __builtin_amdgcn_mfma_f32_16x16x32_bf16(af.v, b0, acc[rt][0], 0, 0, 0);
            acc[rt][1] = __builtin_amdgcn_mfma_f32_16x16x32_bf16(af.v, b1, acc[rt][1], 0, 0, 0);
        }
    }
    unsigned* Yu = (unsigned*)Y16;
    int c = 16 * wave + l16;
#pragma unroll
    for (int rt = 0; rt < 4; ++rt)
#pragma unroll
        for (int r = 0; r < 4; ++r) {
            size_t row = node0 + rt * 16 + quad * 4 + r;
            if (row < (size_t)N)
                Yu[row * 64 + c] = pack_bf16x2(acc[rt][0][r], acc[rt][1][r]);
        }
}

// ---------------- MFMA GEMM, layer 2 (v3: LDS-free) ----------------
// X bf16 [N][128] (out1), Y bf16 [N][64] natural. Block 64 rows x 64 cols;
// wave w: rbase=(w>>1)*32, cbase=(w&1)*32. Whole A-row (8 bf16x8) hoisted.
__global__ __launch_bounds__(256) void gemm2_mfma(const ushort_t* __restrict__ Xb,
                                                  const ushort_t* __restrict__ Wp,
                                                  ushort_t* __restrict__ Y16, int N) {
    int tid = threadIdx.x;
    int wave = tid >> 6, lane = tid & 63;
    int quad = lane >> 4, l16 = lane & 15;
    int rbase = (wave >> 1) * 32, cbase = (wave & 1) * 32;
    size_t node0 = (size_t)blockIdx.x * 64;

    bf16x8 a[2][4];
#pragma unroll
    for (int rt = 0; rt < 2; ++rt) {
        size_t row = node0 + rbase + rt * 16 + l16;
        if (row >= (size_t)N) row = N - 1;
#pragma unroll
        for (int kc = 0; kc < 4; ++kc)
            a[rt][kc] = *(const bf16x8*)(Xb + row * 128 + kc * 32 + quad * 8);
    }

    const ushort_t* b0p = Wp + (size_t)(cbase + l16) * 128;
    const ushort_t* b1p = Wp + (size_t)(cbase + 16 + l16) * 128;

    f32x4 acc[2][2];
#pragma unroll
    for (int rt = 0; rt < 2; ++rt)
#pragma unroll
        for (int ct = 0; ct < 2; ++ct) acc[rt][ct] = (f32x4){0.f, 0.f, 0.f, 0.f};

#pragma unroll
    for (int kc = 0; kc < 4; ++kc) {
        int kb = kc * 32 + quad * 8;
        bf16x8 b0 = *(const bf16x8*)(b0p + kb);
        bf16x8 b1 = *(const bf16x8*)(b1p + kb);
#pragma unroll
        for (int rt = 0; rt < 2; ++rt) {
            acc[rt][0] = __builtin_amdgcn_mfma_f32_16x16x32_bf16(a[rt][kc], b0, acc[rt][0], 0, 0, 0);
            acc[rt][1] = __builtin_amdgcn_mfma_f32_16x16x32_bf16(a[rt][kc], b1, acc[rt][1], 0, 0, 0);
        }
    }
#pragma unroll
    for (int rt = 0; rt < 2; ++rt)
#pragma unroll
        for (int ct = 0; ct < 2; ++ct)
#pragma unroll
            for (int r = 0; r < 4; ++r) {
                size_t row = node0 + rbase + rt * 16 + quad * 4 + r;
                if (row < (size_t)N)
                    Y16[row * 64 + cbase + ct * 16 + l16] = f32_to_bf16(acc[rt][ct][r]);
            }
}

// per-node attention logits from bf16 h: one wave per node.
// H=2 assumes interleaved layout (c*2+h); H=1 plain.
template <int H>
__global__ __launch_bounds__(256) void node_alpha(const ushort_t* __restrict__ H16,
                                                  const float* __restrict__ a_s,
                                                  const float* __restrict__ a_d,
                                                  float* __restrict__ as_out,
                                                  float* __restrict__ ad_out, int N) {
    int wid = threadIdx.x >> 6, lane = threadIdx.x & 63;
    int n = blockIdx.x * 4 + wid;
    if (n >= N) return;
    if (H == 2) {
        const unsigned* hrow = (const unsigned*)(H16 + (size_t)n * 128);
        unsigned u = hrow[lane];
        float h0 = __uint_as_float(u << 16);
        float h1 = __uint_as_float(u & 0xffff0000u);
        float ps0 = h0 * a_s[lane], pd0 = h0 * a_d[lane];
        float ps1 = h1 * a_s[64 + lane], pd1 = h1 * a_d[64 + lane];
#pragma unroll
        for (int off = 32; off; off >>= 1) {
            ps0 += __shfl_xor(ps0, off);
            pd0 += __shfl_xor(pd0, off);
            ps1 += __shfl_xor(ps1, off);
            pd1 += __shfl_xor(pd1, off);
        }
        if (lane == 0) {
            as_out[n * 2 + 0] = ps0; ad_out[n * 2 + 0] = pd0;
            as_out[n * 2 + 1] = ps1; ad_out[n * 2 + 1] = pd1;
        }
    } else {
        float hv = bf16_to_f32(H16[(size_t)n * 64 + lane]);
        float ps = hv * a_s[lane];
        float pd = hv * a_d[lane];
#pragma unroll
        for (int off = 32; off; off >>= 1) {
            ps += __shfl_xor(ps, off);
            pd += __shfl_xor(pd, off);
        }
        if (lane == 0) { as_out[n] = ps; ad_out[n] = pd; }
    }
}

// ---------------- fused gather aggregation ------
// NO max-subtraction (R10 win): |e| <~ 15 by construction, exp safe in fp32;
// self-loops guarantee den > 0. readlane-scalarized edge broadcast (R6 win).
// H=2: weights broadcast as packed bf16x2 -> 2 readlanes/edge (was 3); the
// unpack happens on SALU (SGPR shifts), v_fmac takes the SGPR operand.
template <int H, bool RELU, bool OB16>
__global__ __launch_bounds__(256) void gat_gather(const int* __restrict__ off_end,
                                                  const int* __restrict__ deg,
                                                  const int* __restrict__ csr,
                                                  const float* __restrict__ as,
                                                  const float* __restrict__ ad,
                                                  const ushort_t* __restrict__ H16,
                                                  const float* __restrict__ b,
                                                  void* __restrict__ outp, int N) {
    constexpr int HC = H * 64;
    int wid = threadIdx.x >> 6, lane = threadIdx.x & 63;
    int n = blockIdx.x * 4 + wid;
    if (n >= N) return;
    int dg = deg[n];
    int o = off_end[n] - dg;
    float adv[H];
#pragma unroll
    for (int h = 0; h < H; ++h) adv[h] = ad[n * H + h];

    float acc[H], den[H];
#pragma unroll
    for (int h = 0; h < H; ++h) { acc[h] = 0.f; den[h] = 0.f; }

    const unsigned* Hu = (const unsigned*)H16;  // H==2 interleaved rows (64 u32)

    for (int base = 0; base < dg; base += 64) {
        int i = base + lane;
        bool valid = i < dg;
        int s = valid ? csr[o + i] : 0;
        float v[H];
        if (H == 2) {
            float2 p = valid ? ((const float2*)as)[s] : make_float2(0.f, 0.f);
            v[0] = p.x + adv[0];
            v[H - 1] = p.y + adv[H - 1];
        } else {
            v[0] = valid ? as[s] + adv[0] : 0.f;
        }
#pragma unroll
        for (int h = 0; h < H; ++h) {
            float e = v[h] >= 0.f ? v[h] : NEG_SLOPE * v[h];
            v[h] = valid ? __expf(e) : 0.f;  // weight; 0 for invalid lanes
            den[h] += v[h];
        }
        unsigned wpk = 0;
        if (H == 2) wpk = pack_bf16x2(v[0], v[H - 1]);
        int cnt = min(dg - base, 64);
        int cnt4 = (cnt + 3) & ~3;  // pad: lanes >= cnt have weight 0, s = 0
        for (int j = 0; j < cnt4; j += 4) {
#pragma unroll
            for (int u = 0; u < 4; ++u) {
                int jj = j + u;
                int sj = __builtin_amdgcn_readlane(s, jj);
                if (H == 2) {
                    unsigned wp = (unsigned)__builtin_amdgcn_readlane((int)wpk, jj);
                    float w0 = __uint_as_float(wp << 16);          // SALU (uniform)
                    float w1 = __uint_as_float(wp & 0xffff0000u);  // SALU (uniform)
                    unsigned hu = Hu[(size_t)sj * 64 + lane];
                    acc[0] += w0 * __uint_as_float(hu << 16);
                    acc[H - 1] += w1 * __uint_as_float(hu & 0xffff0000u);
                } else {
                    float w0 = __uint_as_float(
                        __builtin_amdgcn_readlane(__float_as_uint(v[0]), jj));
                    acc[0] += w0 * bf16_to_f32(H16[(size_t)sj * 64 + lane]);
                }
            }
        }
    }
#pragma unroll
    for (int h = 0; h < H; ++h) {
#pragma unroll
        for (int sh = 32; sh; sh >>= 1) den[h] += __shfl_xor(den[h], sh);
        float v = acc[h] / fmaxf(den[h], 1e-16f) + b[h * 64 + lane];
        if (RELU) v = fmaxf(v, 0.f);
        if (OB16)
            ((ushort_t*)outp)[(size_t)n * HC + h * 64 + lane] = f32_to_bf16(v);
        else
            ((float*)outp)[(size_t)n * HC + h * 64 + lane] = v;
    }
}

// ---------------- pooling: batch is SORTED -> segment-local reduce ----------
__global__ __launch_bounds__(256) void pool_nodes(const float* __restrict__ h2,
                                                  const int* __restrict__ batch,
                                                  float* __restrict__ msum,
                                                  unsigned* __restrict__ mmax,
                                                  float* __restrict__ cnt, int N) {
    int wid = threadIdx.x >> 6, lane = threadIdx.x & 63;
    int n0 = (blockIdx.x * 4 + wid) * 64;
    if (n0 >= N) return;
    int n1 = min(n0 + 64, N);
    int curg = batch[n0];
    float s = 0.f, m = -1e30f;
    int c = 0;
    for (int n = n0; n < n1; ++n) {
        int g = batch[n];
        float v = h2[(size_t)n * 64 + lane];
        if (g != curg) {
            atomicAdd(&msum[curg * 64 + lane], s);
            atomicMax(&mmax[curg * 64 + lane], enc_f32(m));
            if (lane == 0) atomicAdd(&cnt[curg], (float)c);
            s = 0.f; m = -1e30f; c = 0; curg = g;
        }
        s += v;
        m = fmaxf(m, v);
        ++c;
    }
    atomicAdd(&msum[curg * 64 + lane], s);
    atomicMax(&mmax[curg * 64 + lane], enc_f32(m));
    if (lane == 0) atomicAdd(&cnt[curg], (float)c);
}

__global__ __launch_bounds__(64) void mlp_head(const float* __restrict__ msum,
                                               const unsigned* __restrict__ mmax,
                                               const float* __restrict__ cnt,
                                               const float* __restrict__ Wf1,
                                               const float* __restrict__ bf1,
                                               const float* __restrict__ Wf2,
                                               const float* __restrict__ bf2,
                                               float* __restrict__ out) {
    __shared__ float pooled[128];
    int g = blockIdx.x, lane = threadIdx.x;
    float c = cnt[g];
    pooled[lane] = msum[g * 64 + lane] / fmaxf(c, 1.0f);
    pooled[64 + lane] = (c > 0.f) ? dec_f32(mmax[g * 64 + lane]) : 0.f;
    __syncthreads();
    float acc = bf1[lane];
#pragma unroll
    for (int k = 0; k < 128; ++k) acc += pooled[k] * Wf1[k * 64 + lane];
    acc = fmaxf(acc, 0.f);
    float r = acc * Wf2[lane];
#pragma unroll
    for (int off = 32; off; off >>= 1) r += __shfl_xor(r, off);
    if (lane == 0) out[g] = r + bf2[0];
}

extern "C" void kernel_launch(void* const* d_in, const int* in_sizes, int n_in,
                              void* d_out, int out_size, void* d_ws, size_t ws_size,
                              hipStream_t stream) {
    const float* x    = (const float*)d_in[0];
    const int*   ei   = (const int*)d_in[1];
    const int*   batch= (const int*)d_in[2];
    const float* W1   = (const float*)d_in[3];
    const float* as1  = (const float*)d_in[4];
    const float* ad1  = (const float*)d_in[5];
    const float* b1   = (const float*)d_in[6];
    const float* W2   = (const float*)d_in[7];
    const float* as2  = (const float*)d_in[8];
    const float* ad2  = (const float*)d_in[9];
    const float* b2   = (const float*)d_in[10];
    const float* Wf1  = (const float*)d_in[11];
    const float* bf1  = (const float*)d_in[12];
    const float* Wf2  = (const float*)d_in[13];
    const float* bf2  = (const float*)d_in[14];
    float* out = (float*)d_out;

    const size_t N = N_NODESC;
    float* ws = (float*)d_ws;
    ushort_t* h16_1 = (ushort_t*)ws;               // N*128 bf16, head-interleaved
    ushort_t* out1b = (ushort_t*)(ws + N * 64);    // N*128 bf16, natural
    ushort_t* h16_2 = (ushort_t*)(ws + N * 128);   // N*64 bf16, natural
    float*    out2  = ws + N * 160;                // N*64 fp32
    float*    small = ws + N * 224;
    float*    as1b = small;                         // 2N
    float*    ad1b = small + 2 * N;                 // 2N
    float*    as2b = small + 4 * N;                 // N
    float*    ad2b = small + 5 * N;                 // N
    float*    msum = small + 6 * N;                 // 512*64
    unsigned* mmax = (unsigned*)(small + 6 * N + 512 * 64);
    float*    cntb = small + 6 * N + 2 * 512 * 64;  // 512
    int* ip  = (int*)(small + 6 * N + 2 * 512 * 64 + 512);
    int* deg  = ip;              // N
    int* off  = ip + N;          // N
    int* csr  = ip + 2 * N;      // E_TOT
    int* bsum = ip + 2 * N + E_TOTC;  // SCAN_NB
    ushort_t* wPre1 = (ushort_t*)(bsum + SCAN_NB);  // 128*128 bf16
    ushort_t* wPre2 = wPre1 + 128 * 128;            // 64*128 bf16

    // init + W pre-convert (single dispatch)
    init_all<<<(N_NODESC + 255) / 256, 256, 0, stream>>>(msum, mmax, cntb, deg,
                                                         W1, W2, wPre1, wPre2);

    // CSR build (reused by both layers); hist includes self-loops
    hist_dst<<<(E_TOTC + 255) / 256, 256, 0, stream>>>(ei, deg);
    scan_partial<<<SCAN_NB, 256, 0, stream>>>(deg, bsum, N);
    scan_final<<<SCAN_NB, 256, 0, stream>>>(deg, bsum, off, N);
    scatter_csr<<<(E_TOTC + 255) / 256, 256, 0, stream>>>(ei, off, csr);

    const int NBLK64 = (N_NODESC + 63) / 64;  // 1563

    // ---- layer 1 (H=2, head-interleaved h16 layout) ----
    gemm1_mfma<<<NBLK64, 256, 0, stream>>>(x, wPre1, h16_1, N);
    node_alpha<2><<<(N + 3) / 4, 256, 0, stream>>>(h16_1, as1, ad1, as1b, ad1b, N);
    gat_gather<2, true, true><<<(N + 3) / 4, 256, 0, stream>>>(off, deg, csr, as1b,
                                                               ad1b, h16_1, b1, out1b, N);

    // ---- layer 2 (H=1) ----
    gemm2_mfma<<<NBLK64, 256, 0, stream>>>(out1b, wPre2, h16_2, N);
    node_alpha<1><<<(N + 3) / 4, 256, 0, stream>>>(h16_2, as2, ad2, as2b, ad2b, N);
    gat_gather<1, false, false><<<(N + 3) / 4, 256, 0, stream>>>(off, deg, csr, as2b,
                                                                 ad2b, h16_2, b2, out2, N);

    // ---- pool + MLP ----
    pool_nodes<<<(N + 255) / 256, 256, 0, stream>>>(out2, batch, msum, mmax, cntb, N);
    mlp_head<<<NUM_GRAPHSC, 64, 0, stream>>>(msum, mmax, cntb, Wf1, bf1, Wf2, bf2, out);
}

// Round 13
// 347.401 us; speedup vs baseline: 1.0825x; 1.0825x over previous
//
#include <hip/hip_runtime.h>

#define N_NODESC 100000
#define N_EDGESC 600000
#define E_TOTC   700000
#define NUM_GRAPHSC 512
#define NEG_SLOPE 0.2f
#define NEG_INF_ENC 0x007FFFFFu
#define SCAN_NB 128

typedef unsigned short ushort_t;
typedef __attribute__((ext_vector_type(8))) short bf16x8;   // 8 bf16 = 4 VGPR
typedef __attribute__((ext_vector_type(4))) float f32x4;    // MFMA accumulator

// monotone float<->uint mapping so unsigned atomicMax == float max
__device__ __forceinline__ unsigned enc_f32(float f) {
    unsigned u = __float_as_uint(f);
    return (u & 0x80000000u) ? ~u : (u | 0x80000000u);
}
__device__ __forceinline__ float dec_f32(unsigned u) {
    u = (u & 0x80000000u) ? (u ^ 0x80000000u) : ~u;
    return __uint_as_float(u);
}
// exact fp32->bf16 RNE (finite values) and bf16->fp32
__device__ __forceinline__ ushort_t f32_to_bf16(float f) {
    unsigned u = __float_as_uint(f);
    return (ushort_t)((u + 0x7FFFu + ((u >> 16) & 1u)) >> 16);
}
__device__ __forceinline__ float bf16_to_f32(ushort_t h) {
    return __uint_as_float(((unsigned)h) << 16);
}
__device__ __forceinline__ unsigned pack_bf16x2(float a, float b) {
    return (unsigned)f32_to_bf16(a) | ((unsigned)f32_to_bf16(b) << 16);
}

// fused init: msum=0, mmax=-inf, cnt=0, deg=0, and W1/W2 -> bf16 in MFMA
// B-fragment layout wPre[n][k] (contiguous 16B per frag -> LDS-free gemms)
__global__ __launch_bounds__(256) void init_all(float* __restrict__ msum,
                                                unsigned* __restrict__ mmax,
                                                float* __restrict__ cnt,
                                                int* __restrict__ deg,
                                                const float* __restrict__ W1,
                                                const float* __restrict__ W2,
                                                ushort_t* __restrict__ wPre1,
                                                ushort_t* __restrict__ wPre2) {
    int i = blockIdx.x * 256 + threadIdx.x;
    if (i < NUM_GRAPHSC * 64) { msum[i] = 0.f; mmax[i] = NEG_INF_ENC; }
    if (i < NUM_GRAPHSC) cnt[i] = 0.f;
    if (i < N_NODESC) deg[i] = 0;
    if (i < 128 * 128) {
        int n = i >> 7, k = i & 127;
        wPre1[n * 128 + k] = f32_to_bf16(W1[k * 128 + n]);
    } else if (i < 128 * 128 + 64 * 128) {
        int j = i - 128 * 128;
        int n = j >> 7, k = j & 127;
        wPre2[n * 128 + k] = f32_to_bf16(W2[k * 64 + n]);
    }
}

// ---------------- CSR build ----------------
__global__ __launch_bounds__(256) void hist_dst(const int* __restrict__ ei,
                                                int* __restrict__ deg) {
    int e = blockIdx.x * blockDim.x + threadIdx.x;
    if (e >= E_TOTC) return;
    int d = (e < N_EDGESC) ? ei[N_EDGESC + e] : e - N_EDGESC;
    atomicAdd(&deg[d], 1);
}

__global__ __launch_bounds__(256) void scan_partial(const int* __restrict__ deg,
                                                    int* __restrict__ bsum, int n) {
    __shared__ int red[256];
    int chunk = (n + SCAN_NB - 1) / SCAN_NB;
    int lo = blockIdx.x * chunk, hi = min(lo + chunk, n);
    int s = 0;
    for (int i = lo + threadIdx.x; i < hi; i += 256) s += deg[i];
    red[threadIdx.x] = s;
    __syncthreads();
    for (int d = 128; d; d >>= 1) {
        if (threadIdx.x < d) red[threadIdx.x] += red[threadIdx.x + d];
        __syncthreads();
    }
    if (threadIdx.x == 0) bsum[blockIdx.x] = red[0];
}

// block-local scan + carry; every block redundantly scans the 128 partials in
// LDS (cheap) -- merges the old scan_bsum dispatch away.
__global__ __launch_bounds__(256) void scan_final(const int* __restrict__ deg,
                                                  const int* __restrict__ bsum,
                                                  int* __restrict__ off, int n) {
    __shared__ int bs[SCAN_NB];
    __shared__ int tile[256];
    __shared__ int carry;
    int t = threadIdx.x;
    if (t < SCAN_NB) bs[t] = bsum[t];
    __syncthreads();
    for (int d = 1; d < SCAN_NB; d <<= 1) {
        int v = (t >= d && t < SCAN_NB) ? bs[t - d] : 0;
        __syncthreads();
        if (t < SCAN_NB) bs[t] += v;
        __syncthreads();
    }
    if (t == 0) carry = blockIdx.x ? bs[blockIdx.x - 1] : 0;
    __syncthreads();
    int chunk = (n + SCAN_NB - 1) / SCAN_NB;
    int lo = blockIdx.x * chunk, hi = min(lo + chunk, n);
    for (int base = lo; base < hi; base += 256) {
        int i = base + t;
        int v = (i < hi) ? deg[i] : 0;
        tile[t] = v;
        __syncthreads();
        for (int d = 1; d < 256; d <<= 1) {
            int u = (t >= d) ? tile[t - d] : 0;
            __syncthreads();
            tile[t] += u;
            __syncthreads();
        }
        if (i < hi) off[i] = carry + tile[t] - v;
        __syncthreads();
        if (t == 0) carry += tile[255];
        __syncthreads();
    }
}

__global__ __launch_bounds__(256) void scatter_csr(const int* __restrict__ ei,
                                                   int* __restrict__ off,
                                                   int* __restrict__ csr) {
    int e = blockIdx.x * blockDim.x + threadIdx.x;
    if (e >= E_TOTC) return;
    int s, d;
    if (e < N_EDGESC) { s = ei[e]; d = ei[N_EDGESC + e]; } else { s = d = e - N_EDGESC; }
    int slot = atomicAdd(&off[d], 1);
    csr[slot] = s;
}

// ---------------- MFMA GEMM, layer 1 (LDS-free, R12) ----------------
__global__ __launch_bounds__(256) void gemm1_mfma(const float* __restrict__ X,
                                                  const ushort_t* __restrict__ Wp,
                                                  ushort_t* __restrict__ Y16, int N) {
    int tid = threadIdx.x;
    int wave = tid >> 6, lane = tid & 63;
    int quad = lane >> 4, l16 = lane & 15;
    size_t node0 = (size_t)blockIdx.x * 64;

    f32x4 acc[4][2];
#pragma unroll
    for (int rt = 0; rt < 4; ++rt)
#pragma unroll
        for (int ct = 0; ct < 2; ++ct) acc[rt][ct] = (f32x4){0.f, 0.f, 0.f, 0.f};

    const ushort_t* w0p = Wp + (size_t)(16 * wave + l16) * 128;
    const ushort_t* w1p = Wp + (size_t)(64 + 16 * wave + l16) * 128;

#pragma unroll
    for (int kc = 0; kc < 4; ++kc) {
        int kb = kc * 32 + quad * 8;
        float4 xa[4], xb[4];
#pragma unroll
        for (int rt = 0; rt < 4; ++rt) {
            size_t row = node0 + rt * 16 + l16;
            if (row >= (size_t)N) row = N - 1;
            const float* xp = X + row * 128 + kb;
            xa[rt] = *(const float4*)xp;
            xb[rt] = *(const float4*)(xp + 4);
        }
        bf16x8 b0 = *(const bf16x8*)(w0p + kb);
        bf16x8 b1 = *(const bf16x8*)(w1p + kb);
#pragma unroll
        for (int rt = 0; rt < 4; ++rt) {
            union { bf16x8 v; unsigned u[4]; } af;
            af.u[0] = pack_bf16x2(xa[rt].x, xa[rt].y);
            af.u[1] = pack_bf16x2(xa[rt].z, xa[rt].w);
            af.u[2] = pack_bf16x2(xb[rt].x, xb[rt].y);
            af.u[3] = pack_bf16x2(xb[rt].z, xb[rt].w);
            acc[rt][0] = __builtin_amdgcn_mfma_f32_16x16x32_bf16(af.v, b0, acc[rt][0], 0, 0, 0);
            acc[rt][1] = __builtin_amdgcn_mfma_f32_16x16x32_bf16(af.v, b1, acc[rt][1], 0, 0, 0);
        }
    }
    unsigned* Yu = (unsigned*)Y16;
    int c = 16 * wave + l16;
#pragma unroll
    for (int rt = 0; rt < 4; ++rt)
#pragma unroll
        for (int r = 0; r < 4; ++r) {
            size_t row = node0 + rt * 16 + quad * 4 + r;
            if (row < (size_t)N)
                Yu[row * 64 + c] = pack_bf16x2(acc[rt][0][r], acc[rt][1][r]);
        }
}

// ---------------- MFMA GEMM, layer 2 (LDS-free, R12) ----------------
__global__ __launch_bounds__(256) void gemm2_mfma(const ushort_t* __restrict__ Xb,
                                                  const ushort_t* __restrict__ Wp,
                                                  ushort_t* __restrict__ Y16, int N) {
    int tid = threadIdx.x;
    int wave = tid >> 6, lane = tid & 63;
    int quad = lane >> 4, l16 = lane & 15;
    int rbase = (wave >> 1) * 32, cbase = (wave & 1) * 32;
    size_t node0 = (size_t)blockIdx.x * 64;

    bf16x8 a[2][4];
#pragma unroll
    for (int rt = 0; rt < 2; ++rt) {
        size_t row = node0 + rbase + rt * 16 + l16;
        if (row >= (size_t)N) row = N - 1;
#pragma unroll
        for (int kc = 0; kc < 4; ++kc)
            a[rt][kc] = *(const bf16x8*)(Xb + row * 128 + kc * 32 + quad * 8);
    }

    const ushort_t* b0p = Wp + (size_t)(cbase + l16) * 128;
    const ushort_t* b1p = Wp + (size_t)(cbase + 16 + l16) * 128;

    f32x4 acc[2][2];
#pragma unroll
    for (int rt = 0; rt < 2; ++rt)
#pragma unroll
        for (int ct = 0; ct < 2; ++ct) acc[rt][ct] = (f32x4){0.f, 0.f, 0.f, 0.f};

#pragma unroll
    for (int kc = 0; kc < 4; ++kc) {
        int kb = kc * 32 + quad * 8;
        bf16x8 b0 = *(const bf16x8*)(b0p + kb);
        bf16x8 b1 = *(const bf16x8*)(b1p + kb);
#pragma unroll
        for (int rt = 0; rt < 2; ++rt) {
            acc[rt][0] = __builtin_amdgcn_mfma_f32_16x16x32_bf16(a[rt][kc], b0, acc[rt][0], 0, 0, 0);
            acc[rt][1] = __builtin_amdgcn_mfma_f32_16x16x32_bf16(a[rt][kc], b1, acc[rt][1], 0, 0, 0);
        }
    }
#pragma unroll
    for (int rt = 0; rt < 2; ++rt)
#pragma unroll
        for (int ct = 0; ct < 2; ++ct)
#pragma unroll
            for (int r = 0; r < 4; ++r) {
                size_t row = node0 + rbase + rt * 16 + quad * 4 + r;
                if (row < (size_t)N)
                    Y16[row * 64 + cbase + ct * 16 + l16] = f32_to_bf16(acc[rt][ct][r]);
            }
}

// per-node attention logits from bf16 h: one wave per node.
// H=2 assumes interleaved layout (c*2+h); H=1 plain.
template <int H>
__global__ __launch_bounds__(256) void node_alpha(const ushort_t* __restrict__ H16,
                                                  const float* __restrict__ a_s,
                                                  const float* __restrict__ a_d,
                                                  float* __restrict__ as_out,
                                                  float* __restrict__ ad_out, int N) {
    int wid = threadIdx.x >> 6, lane = threadIdx.x & 63;
    int n = blockIdx.x * 4 + wid;
    if (n >= N) return;
    if (H == 2) {
        const unsigned* hrow = (const unsigned*)(H16 + (size_t)n * 128);
        unsigned u = hrow[lane];
        float h0 = __uint_as_float(u << 16);
        float h1 = __uint_as_float(u & 0xffff0000u);
        float ps0 = h0 * a_s[lane], pd0 = h0 * a_d[lane];
        float ps1 = h1 * a_s[64 + lane], pd1 = h1 * a_d[64 + lane];
#pragma unroll
        for (int off = 32; off; off >>= 1) {
            ps0 += __shfl_xor(ps0, off);
            pd0 += __shfl_xor(pd0, off);
            ps1 += __shfl_xor(ps1, off);
            pd1 += __shfl_xor(pd1, off);
        }
        if (lane == 0) {
            as_out[n * 2 + 0] = ps0; ad_out[n * 2 + 0] = pd0;
            as_out[n * 2 + 1] = ps1; ad_out[n * 2 + 1] = pd1;
        }
    } else {
        float hv = bf16_to_f32(H16[(size_t)n * 64 + lane]);
        float ps = hv * a_s[lane];
        float pd = hv * a_d[lane];
#pragma unroll
        for (int off = 32; off; off >>= 1) {
            ps += __shfl_xor(ps, off);
            pd += __shfl_xor(pd, off);
        }
        if (lane == 0) { as_out[n] = ps; ad_out[n] = pd; }
    }
}

// ---------------- fused gather aggregation, 16-lane groups ------
// Mean degree = 7 -> wave-per-node wasted 89% of prelude lanes. Now: 16 lanes
// per node, 4 nodes/wave (16/block). Prelude covers 16 edges; den-reduce is 4
// shfl steps; __shfl broadcast uses per-lane index (gbase+j) so ONE bpermute
// serves all 4 groups. Inner x4-unrolled with weight-0 padding (4 row-loads in
// flight; padded lanes have s=0,w=0 -> harmless). Lane loads 16B (H=2) / 8B
// (H=1) of the source row. NO max-subtraction (R10); exp safe by construction.
template <int H, bool RELU, bool OB16>
__global__ __launch_bounds__(256) void gat_gather(const int* __restrict__ off_end,
                                                  const int* __restrict__ deg,
                                                  const int* __restrict__ csr,
                                                  const float* __restrict__ as,
                                                  const float* __restrict__ ad,
                                                  const ushort_t* __restrict__ H16,
                                                  const float* __restrict__ b,
                                                  void* __restrict__ outp, int N) {
    int lane = threadIdx.x & 63;
    int wave = threadIdx.x >> 6;
    int l = lane & 15;          // lane within group
    int gbase = lane & 48;      // group base lane in wave
    int n = blockIdx.x * 16 + wave * 4 + (lane >> 4);
    if (n >= N) return;
    int dg = deg[n];
    int o = off_end[n] - dg;
    float adv[H];
#pragma unroll
    for (int h = 0; h < H; ++h) adv[h] = ad[n * H + h];

    float acc[H][4], den[H];
#pragma unroll
    for (int h = 0; h < H; ++h) {
        den[h] = 0.f;
#pragma unroll
        for (int q = 0; q < 4; ++q) acc[h][q] = 0.f;
    }

    const unsigned* Hu = (const unsigned*)H16;  // H==2: row = 64 u32 interleaved

    for (int base = 0; base < dg; base += 16) {
        int i = base + l;
        bool valid = i < dg;
        int s = valid ? csr[o + i] : 0;
        float v[H];
        if (H == 2) {
            float2 p = valid ? ((const float2*)as)[s] : make_float2(0.f, 0.f);
            v[0] = p.x + adv[0];
            v[H - 1] = p.y + adv[H - 1];
        } else {
            v[0] = valid ? as[s] + adv[0] : 0.f;
        }
#pragma unroll
        for (int h = 0; h < H; ++h) {
            float e = v[h] >= 0.f ? v[h] : NEG_SLOPE * v[h];
            v[h] = valid ? __expf(e) : 0.f;  // weight; 0 for invalid lanes
            den[h] += v[h];
        }
        int wpk = (H == 2) ? (int)pack_bf16x2(v[0], v[H - 1])
                           : (int)__float_as_uint(v[0]);
        int cnt = min(dg - base, 16);
        int cnt4 = (cnt + 3) & ~3;  // pad: lanes >= cnt have weight 0, s = 0
        for (int j = 0; j < cnt4; j += 4) {
#pragma unroll
            for (int u = 0; u < 4; ++u) {
                int src = gbase + j + u;     // per-lane index: serves all groups
                int sj = __shfl(s, src);
                int wp = __shfl(wpk, src);
                if (H == 2) {
                    float w0 = __uint_as_float(((unsigned)wp) << 16);
                    float w1 = __uint_as_float(((unsigned)wp) & 0xffff0000u);
                    uint4 hu = *(const uint4*)(Hu + (size_t)sj * 64 + l * 4);
                    acc[0][0] += w0 * __uint_as_float(hu.x << 16);
                    acc[H - 1][0] += w1 * __uint_as_float(hu.x & 0xffff0000u);
                    acc[0][1] += w0 * __uint_as_float(hu.y << 16);
                    acc[H - 1][1] += w1 * __uint_as_float(hu.y & 0xffff0000u);
                    acc[0][2] += w0 * __uint_as_float(hu.z << 16);
                    acc[H - 1][2] += w1 * __uint_as_float(hu.z & 0xffff0000u);
                    acc[0][3] += w0 * __uint_as_float(hu.w << 16);
                    acc[H - 1][3] += w1 * __uint_as_float(hu.w & 0xffff0000u);
                } else {
                    float w0 = __uint_as_float((unsigned)wp);
                    uint2 hu = *(const uint2*)((const unsigned*)(H16 + (size_t)sj * 64) + l * 2);
                    acc[0][0] += w0 * __uint_as_float(hu.x << 16);
                    acc[0][1] += w0 * __uint_as_float(hu.x & 0xffff0000u);
                    acc[0][2] += w0 * __uint_as_float(hu.y << 16);
                    acc[0][3] += w0 * __uint_as_float(hu.y & 0xffff0000u);
                }
            }
        }
    }
#pragma unroll
    for (int h = 0; h < H; ++h) {
#pragma unroll
        for (int sh = 8; sh; sh >>= 1) den[h] += __shfl_xor(den[h], sh);
    }
    if (H == 2) {
        // natural bf16 out [n][128]: head0 cols l*4..+3, head1 at +64
        float4 b0 = *(const float4*)(b + l * 4);
        float4 b1 = *(const float4*)(b + 64 + l * 4);
        float r0[4], r1[4];
        float id0 = 1.f / fmaxf(den[0], 1e-16f);
        float id1 = 1.f / fmaxf(den[H - 1], 1e-16f);
        r0[0] = acc[0][0] * id0 + b0.x; r0[1] = acc[0][1] * id0 + b0.y;
        r0[2] = acc[0][2] * id0 + b0.z; r0[3] = acc[0][3] * id0 + b0.w;
        r1[0] = acc[H - 1][0] * id1 + b1.x; r1[1] = acc[H - 1][1] * id1 + b1.y;
        r1[2] = acc[H - 1][2] * id1 + b1.z; r1[3] = acc[H - 1][3] * id1 + b1.w;
        if (RELU) {
#pragma unroll
            for (int q = 0; q < 4; ++q) { r0[q] = fmaxf(r0[q], 0.f); r1[q] = fmaxf(r1[q], 0.f); }
        }
        ushort_t* outb = (ushort_t*)outp;
        uint2 p0 = make_uint2(pack_bf16x2(r0[0], r0[1]), pack_bf16x2(r0[2], r0[3]));
        uint2 p1 = make_uint2(pack_bf16x2(r1[0], r1[1]), pack_bf16x2(r1[2], r1[3]));
        *(uint2*)(outb + (size_t)n * 128 + l * 4) = p0;
        *(uint2*)(outb + (size_t)n * 128 + 64 + l * 4) = p1;
    } else {
        float4 bv = *(const float4*)(b + l * 4);
        float id0 = 1.f / fmaxf(den[0], 1e-16f);
        float4 r;
        r.x = acc[0][0] * id0 + bv.x; r.y = acc[0][1] * id0 + bv.y;
        r.z = acc[0][2] * id0 + bv.z; r.w = acc[0][3] * id0 + bv.w;
        if (RELU) { r.x = fmaxf(r.x, 0.f); r.y = fmaxf(r.y, 0.f);
                    r.z = fmaxf(r.z, 0.f); r.w = fmaxf(r.w, 0.f); }
        *(float4*)((float*)outp + (size_t)n * 64 + l * 4) = r;
    }
}

// ---------------- pooling: batch is SORTED -> segment-local reduce ----------
__global__ __launch_bounds__(256) void pool_nodes(const float* __restrict__ h2,
                                                  const int* __restrict__ batch,
                                                  float* __restrict__ msum,
                                                  unsigned* __restrict__ mmax,
                                                  float* __restrict__ cnt, int N) {
    int wid = threadIdx.x >> 6, lane = threadIdx.x & 63;
    int n0 = (blockIdx.x * 4 + wid) * 64;
    if (n0 >= N) return;
    int n1 = min(n0 + 64, N);
    int curg = batch[n0];
    float s = 0.f, m = -1e30f;
    int c = 0;
    for (int n = n0; n < n1; ++n) {
        int g = batch[n];
        float v = h2[(size_t)n * 64 + lane];
        if (g != curg) {
            atomicAdd(&msum[curg * 64 + lane], s);
            atomicMax(&mmax[curg * 64 + lane], enc_f32(m));
            if (lane == 0) atomicAdd(&cnt[curg], (float)c);
            s = 0.f; m = -1e30f; c = 0; curg = g;
        }
        s += v;
        m = fmaxf(m, v);
        ++c;
    }
    atomicAdd(&msum[curg * 64 + lane], s);
    atomicMax(&mmax[curg * 64 + lane], enc_f32(m));
    if (lane == 0) atomicAdd(&cnt[curg], (float)c);
}

__global__ __launch_bounds__(64) void mlp_head(const float* __restrict__ msum,
                                               const unsigned* __restrict__ mmax,
                                               const float* __restrict__ cnt,
                                               const float* __restrict__ Wf1,
                                               const float* __restrict__ bf1,
                                               const float* __restrict__ Wf2,
                                               const float* __restrict__ bf2,
                                               float* __restrict__ out) {
    __shared__ float pooled[128];
    int g = blockIdx.x, lane = threadIdx.x;
    float c = cnt[g];
    pooled[lane] = msum[g * 64 + lane] / fmaxf(c, 1.0f);
    pooled[64 + lane] = (c > 0.f) ? dec_f32(mmax[g * 64 + lane]) : 0.f;
    __syncthreads();
    float acc = bf1[lane];
#pragma unroll
    for (int k = 0; k < 128; ++k) acc += pooled[k] * Wf1[k * 64 + lane];
    acc = fmaxf(acc, 0.f);
    float r = acc * Wf2[lane];
#pragma unroll
    for (int off = 32; off; off >>= 1) r += __shfl_xor(r, off);
    if (lane == 0) out[g] = r + bf2[0];
}

extern "C" void kernel_launch(void* const* d_in, const int* in_sizes, int n_in,
                              void* d_out, int out_size, void* d_ws, size_t ws_size,
                              hipStream_t stream) {
    const float* x    = (const float*)d_in[0];
    const int*   ei   = (const int*)d_in[1];
    const int*   batch= (const int*)d_in[2];
    const float* W1   = (const float*)d_in[3];
    const float* as1  = (const float*)d_in[4];
    const float* ad1  = (const float*)d_in[5];
    const float* b1   = (const float*)d_in[6];
    const float* W2   = (const float*)d_in[7];
    const float* as2  = (const float*)d_in[8];
    const float* ad2  = (const float*)d_in[9];
    const float* b2   = (const float*)d_in[10];
    const float* Wf1  = (const float*)d_in[11];
    const float* bf1  = (const float*)d_in[12];
    const float* Wf2  = (const float*)d_in[13];
    const float* bf2  = (const float*)d_in[14];
    float* out = (float*)d_out;

    const size_t N = N_NODESC;
    float* ws = (float*)d_ws;
    ushort_t* h16_1 = (ushort_t*)ws;               // N*128 bf16, head-interleaved
    ushort_t* out1b = (ushort_t*)(ws + N * 64);    // N*128 bf16, natural
    ushort_t* h16_2 = (ushort_t*)(ws + N * 128);   // N*64 bf16, natural
    float*    out2  = ws + N * 160;                // N*64 fp32
    float*    small = ws + N * 224;
    float*    as1b = small;                         // 2N
    float*    ad1b = small + 2 * N;                 // 2N
    float*    as2b = small + 4 * N;                 // N
    float*    ad2b = small + 5 * N;                 // N
    float*    msum = small + 6 * N;                 // 512*64
    unsigned* mmax = (unsigned*)(small + 6 * N + 512 * 64);
    float*    cntb = small + 6 * N + 2 * 512 * 64;  // 512
    int* ip  = (int*)(small + 6 * N + 2 * 512 * 64 + 512);
    int* deg  = ip;              // N
    int* off  = ip + N;          // N
    int* csr  = ip + 2 * N;      // E_TOT
    int* bsum = ip + 2 * N + E_TOTC;  // SCAN_NB
    ushort_t* wPre1 = (ushort_t*)(bsum + SCAN_NB);  // 128*128 bf16
    ushort_t* wPre2 = wPre1 + 128 * 128;            // 64*128 bf16

    // init + W pre-convert (single dispatch)
    init_all<<<(N_NODESC + 255) / 256, 256, 0, stream>>>(msum, mmax, cntb, deg,
                                                         W1, W2, wPre1, wPre2);

    // CSR build (reused by both layers); hist includes self-loops
    hist_dst<<<(E_TOTC + 255) / 256, 256, 0, stream>>>(ei, deg);
    scan_partial<<<SCAN_NB, 256, 0, stream>>>(deg, bsum, N);
    scan_final<<<SCAN_NB, 256, 0, stream>>>(deg, bsum, off, N);
    scatter_csr<<<(E_TOTC + 255) / 256, 256, 0, stream>>>(ei, off, csr);

    const int NBLK64 = (N_NODESC + 63) / 64;   // 1563
    const int NBLK16 = (N_NODESC + 15) / 16;   // 6250

    // ---- layer 1 (H=2, head-interleaved h16 layout) ----
    gemm1_mfma<<<NBLK64, 256, 0, stream>>>(x, wPre1, h16_1, N);
    node_alpha<2><<<(N + 3) / 4, 256, 0, stream>>>(h16_1, as1, ad1, as1b, ad1b, N);
    gat_gather<2, true, true><<<NBLK16, 256, 0, stream>>>(off, deg, csr, as1b,
                                                          ad1b, h16_1, b1, out1b, N);

    // ---- layer 2 (H=1) ----
    gemm2_mfma<<<NBLK64, 256, 0, stream>>>(out1b, wPre2, h16_2, N);
    node_alpha<1><<<(N + 3) / 4, 256, 0, stream>>>(h16_2, as2, ad2, as2b, ad2b, N);
    gat_gather<1, false, false><<<NBLK16, 256, 0, stream>>>(off, deg, csr, as2b,
                                                            ad2b, h16_2, b2, out2, N);

    // ---- pool + MLP ----
    pool_nodes<<<(N + 255) / 256, 256, 0, stream>>>(out2, batch, msum, mmax, cntb, N);
    mlp_head<<<NUM_GRAPHSC, 64, 0, stream>>>(msum, mmax, cntb, Wf1, bf1, Wf2, bf2, out);
}

// Round 14
// 342.442 us; speedup vs baseline: 1.0981x; 1.0145x over previous
//
#include <hip/hip_runtime.h>

#define N_NODESC 100000
#define N_EDGESC 600000
#define E_TOTC   700000
#define NUM_GRAPHSC 512
#define NEG_SLOPE 0.2f
#define NEG_INF_ENC 0x007FFFFFu
#define SCAN_NB 128

typedef unsigned short ushort_t;
typedef __attribute__((ext_vector_type(8))) short bf16x8;   // 8 bf16 = 4 VGPR
typedef __attribute__((ext_vector_type(4))) float f32x4;    // MFMA accumulator

// monotone float<->uint mapping so unsigned atomicMax == float max
__device__ __forceinline__ unsigned enc_f32(float f) {
    unsigned u = __float_as_uint(f);
    return (u & 0x80000000u) ? ~u : (u | 0x80000000u);
}
__device__ __forceinline__ float dec_f32(unsigned u) {
    u = (u & 0x80000000u) ? (u ^ 0x80000000u) : ~u;
    return __uint_as_float(u);
}
// exact fp32->bf16 RNE (finite values) and bf16->fp32
__device__ __forceinline__ ushort_t f32_to_bf16(float f) {
    unsigned u = __float_as_uint(f);
    return (ushort_t)((u + 0x7FFFu + ((u >> 16) & 1u)) >> 16);
}
__device__ __forceinline__ float bf16_to_f32(ushort_t h) {
    return __uint_as_float(((unsigned)h) << 16);
}
__device__ __forceinline__ unsigned pack_bf16x2(float a, float b) {
    return (unsigned)f32_to_bf16(a) | ((unsigned)f32_to_bf16(b) << 16);
}

// fused init: msum=0, mmax=-inf, cnt=0, deg=0, and W1/W2 -> bf16 in MFMA
// B-fragment layout wPre[n][k] (contiguous 16B per frag -> LDS-free gemms)
__global__ __launch_bounds__(256) void init_all(float* __restrict__ msum,
                                                unsigned* __restrict__ mmax,
                                                float* __restrict__ cnt,
                                                int* __restrict__ deg,
                                                const float* __restrict__ W1,
                                                const float* __restrict__ W2,
                                                ushort_t* __restrict__ wPre1,
                                                ushort_t* __restrict__ wPre2) {
    int i = blockIdx.x * 256 + threadIdx.x;
    if (i < NUM_GRAPHSC * 64) { msum[i] = 0.f; mmax[i] = NEG_INF_ENC; }
    if (i < NUM_GRAPHSC) cnt[i] = 0.f;
    if (i < N_NODESC) deg[i] = 0;
    if (i < 128 * 128) {
        int n = i >> 7, k = i & 127;
        wPre1[n * 128 + k] = f32_to_bf16(W1[k * 128 + n]);
    } else if (i < 128 * 128 + 64 * 128) {
        int j = i - 128 * 128;
        int n = j >> 7, k = j & 127;
        wPre2[n * 128 + k] = f32_to_bf16(W2[k * 64 + n]);
    }
}

// ---------------- CSR build ----------------
__global__ __launch_bounds__(256) void hist_dst(const int* __restrict__ ei,
                                                int* __restrict__ deg) {
    int e = blockIdx.x * blockDim.x + threadIdx.x;
    if (e >= E_TOTC) return;
    int d = (e < N_EDGESC) ? ei[N_EDGESC + e] : e - N_EDGESC;
    atomicAdd(&deg[d], 1);
}

__global__ __launch_bounds__(256) void scan_partial(const int* __restrict__ deg,
                                                    int* __restrict__ bsum, int n) {
    __shared__ int red[256];
    int chunk = (n + SCAN_NB - 1) / SCAN_NB;
    int lo = blockIdx.x * chunk, hi = min(lo + chunk, n);
    int s = 0;
    for (int i = lo + threadIdx.x; i < hi; i += 256) s += deg[i];
    red[threadIdx.x] = s;
    __syncthreads();
    for (int d = 128; d; d >>= 1) {
        if (threadIdx.x < d) red[threadIdx.x] += red[threadIdx.x + d];
        __syncthreads();
    }
    if (threadIdx.x == 0) bsum[blockIdx.x] = red[0];
}

// block-local scan + carry; every block redundantly scans the 128 partials in
// LDS (cheap) -- merges the old scan_bsum dispatch away.
__global__ __launch_bounds__(256) void scan_final(const int* __restrict__ deg,
                                                  const int* __restrict__ bsum,
                                                  int* __restrict__ off, int n) {
    __shared__ int bs[SCAN_NB];
    __shared__ int tile[256];
    __shared__ int carry;
    int t = threadIdx.x;
    if (t < SCAN_NB) bs[t] = bsum[t];
    __syncthreads();
    for (int d = 1; d < SCAN_NB; d <<= 1) {
        int v = (t >= d && t < SCAN_NB) ? bs[t - d] : 0;
        __syncthreads();
        if (t < SCAN_NB) bs[t] += v;
        __syncthreads();
    }
    if (t == 0) carry = blockIdx.x ? bs[blockIdx.x - 1] : 0;
    __syncthreads();
    int chunk = (n + SCAN_NB - 1) / SCAN_NB;
    int lo = blockIdx.x * chunk, hi = min(lo + chunk, n);
    for (int base = lo; base < hi; base += 256) {
        int i = base + t;
        int v = (i < hi) ? deg[i] : 0;
        tile[t] = v;
        __syncthreads();
        for (int d = 1; d < 256; d <<= 1) {
            int u = (t >= d) ? tile[t - d] : 0;
            __syncthreads();
            tile[t] += u;
            __syncthreads();
        }
        if (i < hi) off[i] = carry + tile[t] - v;
        __syncthreads();
        if (t == 0) carry += tile[255];
        __syncthreads();
    }
}

__global__ __launch_bounds__(256) void scatter_csr(const int* __restrict__ ei,
                                                   int* __restrict__ off,
                                                   int* __restrict__ csr) {
    int e = blockIdx.x * blockDim.x + threadIdx.x;
    if (e >= E_TOTC) return;
    int s, d;
    if (e < N_EDGESC) { s = ei[e]; d = ei[N_EDGESC + e]; } else { s = d = e - N_EDGESC; }
    int slot = atomicAdd(&off[d], 1);
    csr[slot] = s;
}

// ---------------- MFMA GEMM, layer 1 (v4: wave-per-16-rows, full-K hoist) ---
// Each wave owns 16 rows x ALL 128 cols (8 col-tiles). A lane's A-data = its
// row's full K = 8 float4, ALL hoisted up front -> one load-latency wait per
// wave (R13 version waited 4x). Per kc: 8 B-frags stream from 64 KB L1/L2-hot
// wPre, 8 independent MFMAs (same A operand, 8 accs) pipeline deeply. A rows
// read once per block (R13: 4x). VGPR ~100 (R3 spill lesson respected).
// Fragment maps (m89/m91): A[m=lane&15][k=quad*8+j], B[n=lane&15][k=quad*8+j],
// D[row=quad*4+r][col=lane&15]. Output head-interleaved u32 (head0 lo, head1 hi):
// u32 col c = ct*16+l16 pairs acc[ct] (head0) with acc[ct+4] (head1).
__global__ __launch_bounds__(256) void gemm1_mfma(const float* __restrict__ X,
                                                  const ushort_t* __restrict__ Wp,
                                                  ushort_t* __restrict__ Y16, int N) {
    int tid = threadIdx.x;
    int wave = tid >> 6, lane = tid & 63;
    int quad = lane >> 4, l16 = lane & 15;
    size_t node0 = (size_t)blockIdx.x * 64 + wave * 16;

    // hoist the lane's entire A row-slice: 4 kc x 2 float4 (32B per kc chunk)
    size_t arow = node0 + l16;
    if (arow >= (size_t)N) arow = N - 1;  // clamp: rows >= N never stored
    const float* xp = X + arow * 128;
    float4 xa[4], xb[4];
#pragma unroll
    for (int kc = 0; kc < 4; ++kc) {
        xa[kc] = *(const float4*)(xp + kc * 32 + quad * 8);
        xb[kc] = *(const float4*)(xp + kc * 32 + quad * 8 + 4);
    }

    f32x4 acc[8];
#pragma unroll
    for (int ct = 0; ct < 8; ++ct) acc[ct] = (f32x4){0.f, 0.f, 0.f, 0.f};

#pragma unroll
    for (int kc = 0; kc < 4; ++kc) {
        int kb = kc * 32 + quad * 8;
        union { bf16x8 v; unsigned u[4]; } af;
        af.u[0] = pack_bf16x2(xa[kc].x, xa[kc].y);
        af.u[1] = pack_bf16x2(xa[kc].z, xa[kc].w);
        af.u[2] = pack_bf16x2(xb[kc].x, xb[kc].y);
        af.u[3] = pack_bf16x2(xb[kc].z, xb[kc].w);
#pragma unroll
        for (int ct = 0; ct < 8; ++ct) {
            bf16x8 b = *(const bf16x8*)(Wp + (size_t)(ct * 16 + l16) * 128 + kb);
            acc[ct] = __builtin_amdgcn_mfma_f32_16x16x32_bf16(af.v, b, acc[ct], 0, 0, 0);
        }
    }
    unsigned* Yu = (unsigned*)Y16;
#pragma unroll
    for (int ct = 0; ct < 4; ++ct) {
        int c = ct * 16 + l16;
#pragma unroll
        for (int r = 0; r < 4; ++r) {
            size_t row = node0 + quad * 4 + r;
            if (row < (size_t)N)
                Yu[row * 64 + c] = pack_bf16x2(acc[ct][r], acc[ct + 4][r]);
        }
    }
}

// ---------------- MFMA GEMM, layer 2 (LDS-free, R12) ----------------
__global__ __launch_bounds__(256) void gemm2_mfma(const ushort_t* __restrict__ Xb,
                                                  const ushort_t* __restrict__ Wp,
                                                  ushort_t* __restrict__ Y16, int N) {
    int tid = threadIdx.x;
    int wave = tid >> 6, lane = tid & 63;
    int quad = lane >> 4, l16 = lane & 15;
    int rbase = (wave >> 1) * 32, cbase = (wave & 1) * 32;
    size_t node0 = (size_t)blockIdx.x * 64;

    bf16x8 a[2][4];
#pragma unroll
    for (int rt = 0; rt < 2; ++rt) {
        size_t row = node0 + rbase + rt * 16 + l16;
        if (row >= (size_t)N) row = N - 1;
#pragma unroll
        for (int kc = 0; kc < 4; ++kc)
            a[rt][kc] = *(const bf16x8*)(Xb + row * 128 + kc * 32 + quad * 8);
    }

    const ushort_t* b0p = Wp + (size_t)(cbase + l16) * 128;
    const ushort_t* b1p = Wp + (size_t)(cbase + 16 + l16) * 128;

    f32x4 acc[2][2];
#pragma unroll
    for (int rt = 0; rt < 2; ++rt)
#pragma unroll
        for (int ct = 0; ct < 2; ++ct) acc[rt][ct] = (f32x4){0.f, 0.f, 0.f, 0.f};

#pragma unroll
    for (int kc = 0; kc < 4; ++kc) {
        int kb = kc * 32 + quad * 8;
        bf16x8 b0 = *(const bf16x8*)(b0p + kb);
        bf16x8 b1 = *(const bf16x8*)(b1p + kb);
#pragma unroll
        for (int rt = 0; rt < 2; ++rt) {
            acc[rt][0] = __builtin_amdgcn_mfma_f32_16x16x32_bf16(a[rt][kc], b0, acc[rt][0], 0, 0, 0);
            acc[rt][1] = __builtin_amdgcn_mfma_f32_16x16x32_bf16(a[rt][kc], b1, acc[rt][1], 0, 0, 0);
        }
    }
#pragma unroll
    for (int rt = 0; rt < 2; ++rt)
#pragma unroll
        for (int ct = 0; ct < 2; ++ct)
#pragma unroll
            for (int r = 0; r < 4; ++r) {
                size_t row = node0 + rbase + rt * 16 + quad * 4 + r;
                if (row < (size_t)N)
                    Y16[row * 64 + cbase + ct * 16 + l16] = f32_to_bf16(acc[rt][ct][r]);
            }
}

// per-node attention logits from bf16 h: one wave per node.
// H=2 assumes interleaved layout (c*2+h); H=1 plain.
template <int H>
__global__ __launch_bounds__(256) void node_alpha(const ushort_t* __restrict__ H16,
                                                  const float* __restrict__ a_s,
                                                  const float* __restrict__ a_d,
                                                  float* __restrict__ as_out,
                                                  float* __restrict__ ad_out, int N) {
    int wid = threadIdx.x >> 6, lane = threadIdx.x & 63;
    int n = blockIdx.x * 4 + wid;
    if (n >= N) return;
    if (H == 2) {
        const unsigned* hrow = (const unsigned*)(H16 + (size_t)n * 128);
        unsigned u = hrow[lane];
        float h0 = __uint_as_float(u << 16);
        float h1 = __uint_as_float(u & 0xffff0000u);
        float ps0 = h0 * a_s[lane], pd0 = h0 * a_d[lane];
        float ps1 = h1 * a_s[64 + lane], pd1 = h1 * a_d[64 + lane];
#pragma unroll
        for (int off = 32; off; off >>= 1) {
            ps0 += __shfl_xor(ps0, off);
            pd0 += __shfl_xor(pd0, off);
            ps1 += __shfl_xor(ps1, off);
            pd1 += __shfl_xor(pd1, off);
        }
        if (lane == 0) {
            as_out[n * 2 + 0] = ps0; ad_out[n * 2 + 0] = pd0;
            as_out[n * 2 + 1] = ps1; ad_out[n * 2 + 1] = pd1;
        }
    } else {
        float hv = bf16_to_f32(H16[(size_t)n * 64 + lane]);
        float ps = hv * a_s[lane];
        float pd = hv * a_d[lane];
#pragma unroll
        for (int off = 32; off; off >>= 1) {
            ps += __shfl_xor(ps, off);
            pd += __shfl_xor(pd, off);
        }
        if (lane == 0) { as_out[n] = ps; ad_out[n] = pd; }
    }
}

// ---------------- fused gather aggregation, 16-lane groups (R13 win) ------
template <int H, bool RELU, bool OB16>
__global__ __launch_bounds__(256) void gat_gather(const int* __restrict__ off_end,
                                                  const int* __restrict__ deg,
                                                  const int* __restrict__ csr,
                                                  const float* __restrict__ as,
                                                  const float* __restrict__ ad,
                                                  const ushort_t* __restrict__ H16,
                                                  const float* __restrict__ b,
                                                  void* __restrict__ outp, int N) {
    int lane = threadIdx.x & 63;
    int wave = threadIdx.x >> 6;
    int l = lane & 15;          // lane within group
    int gbase = lane & 48;      // group base lane in wave
    int n = blockIdx.x * 16 + wave * 4 + (lane >> 4);
    if (n >= N) return;
    int dg = deg[n];
    int o = off_end[n] - dg;
    float adv[H];
#pragma unroll
    for (int h = 0; h < H; ++h) adv[h] = ad[n * H + h];

    float acc[H][4], den[H];
#pragma unroll
    for (int h = 0; h < H; ++h) {
        den[h] = 0.f;
#pragma unroll
        for (int q = 0; q < 4; ++q) acc[h][q] = 0.f;
    }

    const unsigned* Hu = (const unsigned*)H16;  // H==2: row = 64 u32 interleaved

    for (int base = 0; base < dg; base += 16) {
        int i = base + l;
        bool valid = i < dg;
        int s = valid ? csr[o + i] : 0;
        float v[H];
        if (H == 2) {
            float2 p = valid ? ((const float2*)as)[s] : make_float2(0.f, 0.f);
            v[0] = p.x + adv[0];
            v[H - 1] = p.y + adv[H - 1];
        } else {
            v[0] = valid ? as[s] + adv[0] : 0.f;
        }
#pragma unroll
        for (int h = 0; h < H; ++h) {
            float e = v[h] >= 0.f ? v[h] : NEG_SLOPE * v[h];
            v[h] = valid ? __expf(e) : 0.f;  // weight; 0 for invalid lanes
            den[h] += v[h];
        }
        int wpk = (H == 2) ? (int)pack_bf16x2(v[0], v[H - 1])
                           : (int)__float_as_uint(v[0]);
        int cnt = min(dg - base, 16);
        int cnt4 = (cnt + 3) & ~3;  // pad: lanes >= cnt have weight 0, s = 0
        for (int j = 0; j < cnt4; j += 4) {
#pragma unroll
            for (int u = 0; u < 4; ++u) {
                int src = gbase + j + u;     // per-lane index: serves all groups
                int sj = __shfl(s, src);
                int wp = __shfl(wpk, src);
                if (H == 2) {
                    float w0 = __uint_as_float(((unsigned)wp) << 16);
                    float w1 = __uint_as_float(((unsigned)wp) & 0xffff0000u);
                    uint4 hu = *(const uint4*)(Hu + (size_t)sj * 64 + l * 4);
                    acc[0][0] += w0 * __uint_as_float(hu.x << 16);
                    acc[H - 1][0] += w1 * __uint_as_float(hu.x & 0xffff0000u);
                    acc[0][1] += w0 * __uint_as_float(hu.y << 16);
                    acc[H - 1][1] += w1 * __uint_as_float(hu.y & 0xffff0000u);
                    acc[0][2] += w0 * __uint_as_float(hu.z << 16);
                    acc[H - 1][2] += w1 * __uint_as_float(hu.z & 0xffff0000u);
                    acc[0][3] += w0 * __uint_as_float(hu.w << 16);
                    acc[H - 1][3] += w1 * __uint_as_float(hu.w & 0xffff0000u);
                } else {
                    float w0 = __uint_as_float((unsigned)wp);
                    uint2 hu = *(const uint2*)((const unsigned*)(H16 + (size_t)sj * 64) + l * 2);
                    acc[0][0] += w0 * __uint_as_float(hu.x << 16);
                    acc[0][1] += w0 * __uint_as_float(hu.x & 0xffff0000u);
                    acc[0][2] += w0 * __uint_as_float(hu.y << 16);
                    acc[0][3] += w0 * __uint_as_float(hu.y & 0xffff0000u);
                }
            }
        }
    }
#pragma unroll
    for (int h = 0; h < H; ++h) {
#pragma unroll
        for (int sh = 8; sh; sh >>= 1) den[h] += __shfl_xor(den[h], sh);
    }
    if (H == 2) {
        // natural bf16 out [n][128]: head0 cols l*4..+3, head1 at +64
        float4 b0 = *(const float4*)(b + l * 4);
        float4 b1 = *(const float4*)(b + 64 + l * 4);
        float r0[4], r1[4];
        float id0 = 1.f / fmaxf(den[0], 1e-16f);
        float id1 = 1.f / fmaxf(den[H - 1], 1e-16f);
        r0[0] = acc[0][0] * id0 + b0.x; r0[1] = acc[0][1] * id0 + b0.y;
        r0[2] = acc[0][2] * id0 + b0.z; r0[3] = acc[0][3] * id0 + b0.w;
        r1[0] = acc[H - 1][0] * id1 + b1.x; r1[1] = acc[H - 1][1] * id1 + b1.y;
        r1[2] = acc[H - 1][2] * id1 + b1.z; r1[3] = acc[H - 1][3] * id1 + b1.w;
        if (RELU) {
#pragma unroll
            for (int q = 0; q < 4; ++q) { r0[q] = fmaxf(r0[q], 0.f); r1[q] = fmaxf(r1[q], 0.f); }
        }
        ushort_t* outb = (ushort_t*)outp;
        uint2 p0 = make_uint2(pack_bf16x2(r0[0], r0[1]), pack_bf16x2(r0[2], r0[3]));
        uint2 p1 = make_uint2(pack_bf16x2(r1[0], r1[1]), pack_bf16x2(r1[2], r1[3]));
        *(uint2*)(outb + (size_t)n * 128 + l * 4) = p0;
        *(uint2*)(outb + (size_t)n * 128 + 64 + l * 4) = p1;
    } else {
        float4 bv = *(const float4*)(b + l * 4);
        float id0 = 1.f / fmaxf(den[0], 1e-16f);
        float4 r;
        r.x = acc[0][0] * id0 + bv.x; r.y = acc[0][1] * id0 + bv.y;
        r.z = acc[0][2] * id0 + bv.z; r.w = acc[0][3] * id0 + bv.w;
        if (RELU) { r.x = fmaxf(r.x, 0.f); r.y = fmaxf(r.y, 0.f);
                    r.z = fmaxf(r.z, 0.f); r.w = fmaxf(r.w, 0.f); }
        *(float4*)((float*)outp + (size_t)n * 64 + l * 4) = r;
    }
}

// ---------------- pooling: batch is SORTED -> segment-local reduce ----------
__global__ __launch_bounds__(256) void pool_nodes(const float* __restrict__ h2,
                                                  const int* __restrict__ batch,
                                                  float* __restrict__ msum,
                                                  unsigned* __restrict__ mmax,
                                                  float* __restrict__ cnt, int N) {
    int wid = threadIdx.x >> 6, lane = threadIdx.x & 63;
    int n0 = (blockIdx.x * 4 + wid) * 64;
    if (n0 >= N) return;
    int n1 = min(n0 + 64, N);
    int curg = batch[n0];
    float s = 0.f, m = -1e30f;
    int c = 0;
    for (int n = n0; n < n1; ++n) {
        int g = batch[n];
        float v = h2[(size_t)n * 64 + lane];
        if (g != curg) {
            atomicAdd(&msum[curg * 64 + lane], s);
            atomicMax(&mmax[curg * 64 + lane], enc_f32(m));
            if (lane == 0) atomicAdd(&cnt[curg], (float)c);
            s = 0.f; m = -1e30f; c = 0; curg = g;
        }
        s += v;
        m = fmaxf(m, v);
        ++c;
    }
    atomicAdd(&msum[curg * 64 + lane], s);
    atomicMax(&mmax[curg * 64 + lane], enc_f32(m));
    if (lane == 0) atomicAdd(&cnt[curg], (float)c);
}

__global__ __launch_bounds__(64) void mlp_head(const float* __restrict__ msum,
                                               const unsigned* __restrict__ mmax,
                                               const float* __restrict__ cnt,
                                               const float* __restrict__ Wf1,
                                               const float* __restrict__ bf1,
                                               const float* __restrict__ Wf2,
                                               const float* __restrict__ bf2,
                                               float* __restrict__ out) {
    __shared__ float pooled[128];
    int g = blockIdx.x, lane = threadIdx.x;
    float c = cnt[g];
    pooled[lane] = msum[g * 64 + lane] / fmaxf(c, 1.0f);
    pooled[64 + lane] = (c > 0.f) ? dec_f32(mmax[g * 64 + lane]) : 0.f;
    __syncthreads();
    float acc = bf1[lane];
#pragma unroll
    for (int k = 0; k < 128; ++k) acc += pooled[k] * Wf1[k * 64 + lane];
    acc = fmaxf(acc, 0.f);
    float r = acc * Wf2[lane];
#pragma unroll
    for (int off = 32; off; off >>= 1) r += __shfl_xor(r, off);
    if (lane == 0) out[g] = r + bf2[0];
}

extern "C" void kernel_launch(void* const* d_in, const int* in_sizes, int n_in,
                              void* d_out, int out_size, void* d_ws, size_t ws_size,
                              hipStream_t stream) {
    const float* x    = (const float*)d_in[0];
    const int*   ei   = (const int*)d_in[1];
    const int*   batch= (const int*)d_in[2];
    const float* W1   = (const float*)d_in[3];
    const float* as1  = (const float*)d_in[4];
    const float* ad1  = (const float*)d_in[5];
    const float* b1   = (const float*)d_in[6];
    const float* W2   = (const float*)d_in[7];
    const float* as2  = (const float*)d_in[8];
    const float* ad2  = (const float*)d_in[9];
    const float* b2   = (const float*)d_in[10];
    const float* Wf1  = (const float*)d_in[11];
    const float* bf1  = (const float*)d_in[12];
    const float* Wf2  = (const float*)d_in[13];
    const float* bf2  = (const float*)d_in[14];
    float* out = (float*)d_out;

    const size_t N = N_NODESC;
    float* ws = (float*)d_ws;
    ushort_t* h16_1 = (ushort_t*)ws;               // N*128 bf16, head-interleaved
    ushort_t* out1b = (ushort_t*)(ws + N * 64);    // N*128 bf16, natural
    ushort_t* h16_2 = (ushort_t*)(ws + N * 128);   // N*64 bf16, natural
    float*    out2  = ws + N * 160;                // N*64 fp32
    float*    small = ws + N * 224;
    float*    as1b = small;                         // 2N
    float*    ad1b = small + 2 * N;                 // 2N
    float*    as2b = small + 4 * N;                 // N
    float*    ad2b = small + 5 * N;                 // N
    float*    msum = small + 6 * N;                 // 512*64
    unsigned* mmax = (unsigned*)(small + 6 * N + 512 * 64);
    float*    cntb = small + 6 * N + 2 * 512 * 64;  // 512
    int* ip  = (int*)(small + 6 * N + 2 * 512 * 64 + 512);
    int* deg  = ip;              // N
    int* off  = ip + N;          // N
    int* csr  = ip + 2 * N;      // E_TOT
    int* bsum = ip + 2 * N + E_TOTC;  // SCAN_NB
    ushort_t* wPre1 = (ushort_t*)(bsum + SCAN_NB);  // 128*128 bf16
    ushort_t* wPre2 = wPre1 + 128 * 128;            // 64*128 bf16

    // init + W pre-convert (single dispatch)
    init_all<<<(N_NODESC + 255) / 256, 256, 0, stream>>>(msum, mmax, cntb, deg,
                                                         W1, W2, wPre1, wPre2);

    // CSR build (reused by both layers); hist includes self-loops
    hist_dst<<<(E_TOTC + 255) / 256, 256, 0, stream>>>(ei, deg);
    scan_partial<<<SCAN_NB, 256, 0, stream>>>(deg, bsum, N);
    scan_final<<<SCAN_NB, 256, 0, stream>>>(deg, bsum, off, N);
    scatter_csr<<<(E_TOTC + 255) / 256, 256, 0, stream>>>(ei, off, csr);

    const int NBLK64 = (N_NODESC + 63) / 64;   // 1563
    const int NBLK16 = (N_NODESC + 15) / 16;   // 6250

    // ---- layer 1 (H=2, head-interleaved h16 layout) ----
    gemm1_mfma<<<NBLK64, 256, 0, stream>>>(x, wPre1, h16_1, N);
    node_alpha<2><<<(N + 3) / 4, 256, 0, stream>>>(h16_1, as1, ad1, as1b, ad1b, N);
    gat_gather<2, true, true><<<NBLK16, 256, 0, stream>>>(off, deg, csr, as1b,
                                                          ad1b, h16_1, b1, out1b, N);

    // ---- layer 2 (H=1) ----
    gemm2_mfma<<<NBLK64, 256, 0, stream>>>(out1b, wPre2, h16_2, N);
    node_alpha<1><<<(N + 3) / 4, 256, 0, stream>>>(h16_2, as2, ad2, as2b, ad2b, N);
    gat_gather<1, false, false><<<NBLK16, 256, 0, stream>>>(off, deg, csr, as2b,
                                                            ad2b, h16_2, b2, out2, N);

    // ---- pool + MLP ----
    pool_nodes<<<(N + 255) / 256, 256, 0, stream>>>(out2, batch, msum, mmax, cntb, N);
    mlp_head<<<NUM_GRAPHSC, 64, 0, stream>>>(msum, mmax, cntb, Wf1, bf1, Wf2, bf2, out);
}